// Round 4
// baseline (440.599 us; speedup 1.0000x reference)
//
#include <hip/hip_runtime.h>
#include <cstdint>

#define IMG_H 512
#define IMG_W 512
#define ROW_BYTES (IMG_W * 4)
#define NPLANES 48                  // 16 batch * 3 channels
#define PLANE_SZ (IMG_H * IMG_W)
#define N_ELEM (NPLANES * PLANE_SZ) // 12,582,912

#define TILE_W 48
#define TILE_H 32
#define GX 11
#define GY 16
#define NBLOCKS (GX * GY * NPLANES) // 8448 = 33 * 256 exactly
#define VPITCH 59                   // stored halo cols 0..57 (+1 pad)

#define SSIM_C1 1e-4f
#define SSIM_C2 9e-4f

// Raw buffer load: OOB (row<0 / row>=H via soffset; bad col via huge voffset)
// returns 0.0f in hardware = free 'SAME' zero padding, zero bounds VALU.
typedef int rsrc_t __attribute__((ext_vector_type(4)));
__device__ float
llvm_amdgcn_raw_buffer_load_fp32(rsrc_t srsrc, int voffset, int soffset,
                                 int glc_slc) __asm("llvm.amdgcn.raw.buffer.load.f32");

__device__ inline rsrc_t make_rsrc(const void* p, int bytes) {
    rsrc_t r;
    r.x = (int)(uint32_t)(uintptr_t)p;       // base lo
    r.y = (int)((uintptr_t)p >> 32);         // base hi, stride=0
    r.z = bytes;                             // num_records (bytes)
    r.w = 0x00020000;                        // raw dword SRD word3
    return r;
}

// Separable 11x11 Gaussian over 4 channels (s=x+y, d=x-y, s^2, d^2),
// SSIM map, per-block partial, last-block-done fused finalize.
//
// R8 post-mortem trail: TILE_H=16 (R5) raised occupancy 42->70% but was
// time-neutral (added 55% vertical-prep redundancy). Packed f32x2 (R6/R7)
// was a dead end: gfx950 FP32 peak 157.3TF == plain v_fma_f32 rate, so
// v_pk_fma_f32 saves issue slots but not execution cycles, and we're near
// the FP32 execution pipe (~31us VALU-busy vs ~17us algorithmic floor).
// So: revert to the best-measured R0 structure (TILE_H=32, scalar fmaf,
// (256,4)) and instead fuse the finalize kernel (saves launch gap + 1-block
// kernel latency ~8-12us of bench time, off the tile critical path).
__global__ __launch_bounds__(256, 4) void ssim_tile_kernel(
    const float* __restrict__ img1, const float* __restrict__ img2,
    double* __restrict__ partials, unsigned int* __restrict__ cnt,
    float* __restrict__ out)
{
    __shared__ float4 vs[TILE_H][VPITCH]; // 30.2 KB -> 5 blocks/CU
    __shared__ double wred[4];
    __shared__ unsigned int isLast;

    // exact gaussian(ws=11, sigma=1.5) weights (normalized, ~1e-8 abs)
    const float gw[11] = {0.00102838f, 0.00759876f, 0.03600077f, 0.10936069f,
                          0.21300553f, 0.26601172f, 0.21300553f, 0.10936069f,
                          0.03600077f, 0.00759876f, 0.00102838f};

    const int tid  = threadIdx.x;
    const int lane = tid & 63;
    const int wv   = tid >> 6;
    const int ox = blockIdx.x * TILE_W;
    const int oy = blockIdx.y * TILE_H;

    const float* p1 = img1 + (size_t)blockIdx.z * PLANE_SZ;
    const float* p2 = img2 + (size_t)blockIdx.z * PLANE_SZ;
    const rsrc_t rr1 = make_rsrc(p1, PLANE_SZ * 4);
    const rsrc_t rr2 = make_rsrc(p2, PLANE_SZ * 4);

    // ---- vertical pass: wave wv -> output rows [oy+wv*8, +8), lane = halo col
    {
        const int r0 = wv * 8;
        const int srow0 = __builtin_amdgcn_readfirstlane(oy + r0 - 5); // SGPR
        const int gcol = ox + lane - 5;
        // lanes >= 58 are never consumed by the horizontal pass: mask their
        // (otherwise in-bounds) loads too -> less vertical fetch traffic.
        const int coff = (lane < 58 && (unsigned)gcol < (unsigned)IMG_W)
                             ? (gcol * 4) : 0x48000000;

        // Stage 1: issue loads with max memory-level parallelism
        float xs[18], ys[18];
        #pragma unroll
        for (int i = 0; i < 18; ++i) {
            const int soff = (srow0 + i) * ROW_BYTES;  // SGPR soffset
            xs[i] = llvm_amdgcn_raw_buffer_load_fp32(rr1, coff, soff, 0);
            ys[i] = llvm_amdgcn_raw_buffer_load_fp32(rr2, coff, soff, 0);
        }

        // Stage 2: consume
        float4 acc[8];
        #pragma unroll
        for (int o = 0; o < 8; ++o) acc[o] = make_float4(0.f, 0.f, 0.f, 0.f);
        #pragma unroll
        for (int i = 0; i < 18; ++i) {
            const float s = xs[i] + ys[i], d = xs[i] - ys[i];
            const float s2 = s * s, d2 = d * d;
            #pragma unroll
            for (int o = 0; o < 8; ++o) {
                const int k = i - o;              // tap index (static)
                if (k >= 0 && k <= 10) {
                    const float w = gw[k];
                    acc[o].x = fmaf(w, s,  acc[o].x);
                    acc[o].y = fmaf(w, d,  acc[o].y);
                    acc[o].z = fmaf(w, s2, acc[o].z);
                    acc[o].w = fmaf(w, d2, acc[o].w);
                }
            }
        }
        if (lane < 58) {                          // only cols used by horizontal
            #pragma unroll
            for (int o = 0; o < 8; ++o) vs[r0 + o][lane] = acc[o];
        }
    }
    __syncthreads();

    // ---- horizontal pass + SSIM: thread -> 1 row x 6 consecutive cols
    float lsum = 0.f;
    {
        const int r  = tid >> 3;
        const int c0 = (tid & 7) * 6;            // max read col 42+15=57 < 58
        float4 m[6];
        #pragma unroll
        for (int j = 0; j < 6; ++j) m[j] = make_float4(0.f, 0.f, 0.f, 0.f);
        #pragma unroll
        for (int t = 0; t < 16; ++t) {
            const float4 v = vs[r][c0 + t];
            #pragma unroll
            for (int j = 0; j < 6; ++j) {
                const int k = t - j;
                if (k >= 0 && k <= 10) {
                    const float w = gw[k];
                    m[j].x = fmaf(w, v.x, m[j].x);
                    m[j].y = fmaf(w, v.y, m[j].y);
                    m[j].z = fmaf(w, v.z, m[j].z);
                    m[j].w = fmaf(w, v.w, m[j].w);
                }
            }
        }
        #pragma unroll
        for (int j = 0; j < 6; ++j) {
            if (ox + c0 + j < IMG_W) {           // clip right-edge partial tile
                const float mus = m[j].x, mud = m[j].y;
                const float es2 = m[j].z, ed2 = m[j].w;
                const float a = mus * mus, b = mud * mud;
                // mu1 = (mus+mud)/2, mu2 = (mus-mud)/2:
                const float num1 = (a - b) * 0.5f + SSIM_C1;               // 2*mu1*mu2 + C1
                const float den1 = (a + b) * 0.5f + SSIM_C1;               // mu1^2+mu2^2 + C1
                const float num2 = (es2 - ed2 - (a - b)) * 0.5f + SSIM_C2; // 2*sigma12 + C2
                const float den2 = (es2 + ed2 - (a + b)) * 0.5f + SSIM_C2; // s1+s2 + C2
                lsum += (num1 * num2) * __builtin_amdgcn_rcpf(den1 * den2);
            }
        }
    }

    // ---- block reduction -> one partial per block, plain store (no atomics)
    #pragma unroll
    for (int off = 32; off > 0; off >>= 1)
        lsum += __shfl_down(lsum, off, 64);
    if (lane == 0) wred[wv] = (double)lsum;
    __syncthreads();
    if (tid == 0) {
        const int bid = blockIdx.x + GX * (blockIdx.y + GY * blockIdx.z);
        partials[bid] = wred[0] + wred[1] + wred[2] + wred[3];
        __threadfence();                          // partials visible device-wide
        const unsigned int old = atomicAdd(cnt, 1u);
        isLast = (old == NBLOCKS - 1) ? 1u : 0u;
    }
    __syncthreads();

    // ---- fused finalize: the last-arriving block reduces all partials
    if (isLast) {
        __threadfence();                          // acquire: see all partials
        double s = 0.0;
        #pragma unroll
        for (int i = 0; i < 33; ++i)              // 33 * 256 == 8448, no bounds
            s += partials[tid + i * 256];
        #pragma unroll
        for (int off = 32; off > 0; off >>= 1)
            s += __shfl_down(s, off, 64);
        __shared__ double fred[4];
        if (lane == 0) fred[wv] = s;
        __syncthreads();
        if (tid == 0)
            out[0] = (float)((fred[0] + fred[1] + fred[2] + fred[3])
                             / (double)N_ELEM);
    }
}

extern "C" void kernel_launch(void* const* d_in, const int* in_sizes, int n_in,
                              void* d_out, int out_size, void* d_ws, size_t ws_size,
                              hipStream_t stream)
{
    const float* img1 = (const float*)d_in[0];
    const float* img2 = (const float*)d_in[1];
    double* partials  = (double*)d_ws;           // 8448 * 8B = 67.6 KB scratch
    unsigned int* cnt = (unsigned int*)(partials + NBLOCKS);
    float* out        = (float*)d_out;

    // counter must be 0 at kernel start every iteration (graph-capture-safe)
    hipMemsetAsync(cnt, 0, sizeof(unsigned int), stream);

    dim3 grid(GX, GY, NPLANES);
    ssim_tile_kernel<<<grid, dim3(256), 0, stream>>>(img1, img2, partials, cnt, out);
}

// Round 5
// 138.194 us; speedup vs baseline: 3.1883x; 3.1883x over previous
//
#include <hip/hip_runtime.h>
#include <cstdint>

#define IMG_H 512
#define IMG_W 512
#define ROW_BYTES (IMG_W * 4)
#define NPLANES 48                  // 16 batch * 3 channels
#define PLANE_SZ (IMG_H * IMG_W)
#define N_ELEM (NPLANES * PLANE_SZ) // 12,582,912

#define TILE_W 48
#define TILE_H 32                   // rows per sub-tile; block does 2 stacked
#define GX 11
#define GYB 8                       // y-blocks of 64 rows (2 x 32)
#define NBLOCKS (GX * GYB * NPLANES) // 4224
#define VPITCH 59                   // stored halo cols 0..57 (+1 pad)

#define SSIM_C1 1e-4f
#define SSIM_C2 9e-4f

// Raw buffer load: OOB (row<0 / row>=H via soffset; bad col via huge voffset)
// returns 0.0f in hardware = free 'SAME' zero padding, zero bounds VALU.
typedef int rsrc_t __attribute__((ext_vector_type(4)));
__device__ float
llvm_amdgcn_raw_buffer_load_fp32(rsrc_t srsrc, int voffset, int soffset,
                                 int glc_slc) __asm("llvm.amdgcn.raw.buffer.load.f32");

__device__ inline rsrc_t make_rsrc(const void* p, int bytes) {
    rsrc_t r;
    r.x = (int)(uint32_t)(uintptr_t)p;       // base lo
    r.y = (int)((uintptr_t)p >> 32);         // base hi, stride=0
    r.z = bytes;                             // num_records (bytes)
    r.w = 0x00020000;                        // raw dword SRD word3
    return r;
}

// Separable 11x11 Gaussian over 4 channels (s=x+y, d=x-y, s^2, d^2),
// SSIM map, per-block partial.
//
// Journal: R5 occupancy boost neutral; R6/R7 pk-fp32 dead end (not double
// rate on CDNA4); R8 fused finalize catastrophic (single-line device atomic
// serializes ~40ns x 8448 blocks across 8 XCDs). R9 = R0 structure + in-block
// 2-tile software pipeline: issue tile-1's 36 buffer loads AFTER tile-0's
// barrier but BEFORE tile-0's horizontal pass (no VMEM ops in horizontal ->
// loads stay in flight across ~700 VALU cycles), so tile-1's consume starts
// with latency already paid. Op count identical to R0; blocks halved.
__global__ __launch_bounds__(256, 4) void ssim_tile_kernel(
    const float* __restrict__ img1, const float* __restrict__ img2,
    double* __restrict__ partials)
{
    __shared__ float4 vs[TILE_H][VPITCH]; // 30.2 KB -> 5 blocks/CU
    __shared__ double wred[4];

    // exact gaussian(ws=11, sigma=1.5) weights (normalized, ~1e-8 abs)
    const float gw[11] = {0.00102838f, 0.00759876f, 0.03600077f, 0.10936069f,
                          0.21300553f, 0.26601172f, 0.21300553f, 0.10936069f,
                          0.03600077f, 0.00759876f, 0.00102838f};

    const int tid  = threadIdx.x;
    const int lane = tid & 63;
    const int wv   = tid >> 6;
    const int ox  = blockIdx.x * TILE_W;
    const int oy0 = blockIdx.y * (2 * TILE_H);   // this block: rows [oy0, oy0+64)

    const float* p1 = img1 + (size_t)blockIdx.z * PLANE_SZ;
    const float* p2 = img2 + (size_t)blockIdx.z * PLANE_SZ;
    const rsrc_t rr1 = make_rsrc(p1, PLANE_SZ * 4);
    const rsrc_t rr2 = make_rsrc(p2, PLANE_SZ * 4);

    const int gcol = ox + lane - 5;
    // lanes >= 58 never consumed by horizontal: mask their loads too.
    const int coff = (lane < 58 && (unsigned)gcol < (unsigned)IMG_W)
                         ? (gcol * 4) : 0x48000000;

    // ---- prologue: issue ALL 36 loads for sub-tile 0 (max MLP)
    float xs[18], ys[18];
    {
        const int srow0 = __builtin_amdgcn_readfirstlane(oy0 + wv * 8 - 5);
        #pragma unroll
        for (int i = 0; i < 18; ++i) {
            const int soff = (srow0 + i) * ROW_BYTES;   // SGPR soffset
            xs[i] = llvm_amdgcn_raw_buffer_load_fp32(rr1, coff, soff, 0);
            ys[i] = llvm_amdgcn_raw_buffer_load_fp32(rr2, coff, soff, 0);
        }
    }

    float lsum = 0.f;
    #pragma unroll
    for (int ty = 0; ty < 2; ++ty) {
        // ---- vertical pass: wave wv -> rows [wv*8, +8) of this sub-tile
        {
            const int r0 = wv * 8;
            float4 acc[8];
            #pragma unroll
            for (int o = 0; o < 8; ++o) acc[o] = make_float4(0.f, 0.f, 0.f, 0.f);
            #pragma unroll
            for (int i = 0; i < 18; ++i) {
                const float s = xs[i] + ys[i], d = xs[i] - ys[i];
                const float s2 = s * s, d2 = d * d;
                #pragma unroll
                for (int o = 0; o < 8; ++o) {
                    const int k = i - o;              // tap index (static)
                    if (k >= 0 && k <= 10) {
                        const float w = gw[k];
                        acc[o].x = fmaf(w, s,  acc[o].x);
                        acc[o].y = fmaf(w, d,  acc[o].y);
                        acc[o].z = fmaf(w, s2, acc[o].z);
                        acc[o].w = fmaf(w, d2, acc[o].w);
                    }
                }
            }
            if (lane < 58) {                          // only cols horizontal uses
                #pragma unroll
                for (int o = 0; o < 8; ++o) vs[r0 + o][lane] = acc[o];
            }
        }
        __syncthreads();

        // ---- prefetch: issue sub-tile 1's 36 loads NOW; they stay in flight
        // across the horizontal pass below (no VMEM ops there -> no vmcnt wait).
        if (ty == 0) {
            const int srow1 =
                __builtin_amdgcn_readfirstlane(oy0 + TILE_H + wv * 8 - 5);
            #pragma unroll
            for (int i = 0; i < 18; ++i) {
                const int soff = (srow1 + i) * ROW_BYTES;
                xs[i] = llvm_amdgcn_raw_buffer_load_fp32(rr1, coff, soff, 0);
                ys[i] = llvm_amdgcn_raw_buffer_load_fp32(rr2, coff, soff, 0);
            }
        }

        // ---- horizontal pass + SSIM: thread -> 1 row x 6 consecutive cols
        {
            const int r  = tid >> 3;
            const int c0 = (tid & 7) * 6;            // max read col 42+15=57 < 58
            float4 m[6];
            #pragma unroll
            for (int j = 0; j < 6; ++j) m[j] = make_float4(0.f, 0.f, 0.f, 0.f);
            #pragma unroll
            for (int t = 0; t < 16; ++t) {
                const float4 v = vs[r][c0 + t];
                #pragma unroll
                for (int j = 0; j < 6; ++j) {
                    const int k = t - j;
                    if (k >= 0 && k <= 10) {
                        const float w = gw[k];
                        m[j].x = fmaf(w, v.x, m[j].x);
                        m[j].y = fmaf(w, v.y, m[j].y);
                        m[j].z = fmaf(w, v.z, m[j].z);
                        m[j].w = fmaf(w, v.w, m[j].w);
                    }
                }
            }
            #pragma unroll
            for (int j = 0; j < 6; ++j) {
                if (ox + c0 + j < IMG_W) {           // clip right-edge partial tile
                    const float mus = m[j].x, mud = m[j].y;
                    const float es2 = m[j].z, ed2 = m[j].w;
                    const float a = mus * mus, b = mud * mud;
                    // mu1 = (mus+mud)/2, mu2 = (mus-mud)/2:
                    const float num1 = (a - b) * 0.5f + SSIM_C1;               // 2*mu1*mu2 + C1
                    const float den1 = (a + b) * 0.5f + SSIM_C1;               // mu1^2+mu2^2 + C1
                    const float num2 = (es2 - ed2 - (a - b)) * 0.5f + SSIM_C2; // 2*sigma12 + C2
                    const float den2 = (es2 + ed2 - (a + b)) * 0.5f + SSIM_C2; // s1+s2 + C2
                    lsum += (num1 * num2) * __builtin_amdgcn_rcpf(den1 * den2);
                }
            }
        }
        // WAR: next iteration's vertical writes vs; all horiz reads must finish.
        if (ty == 0) __syncthreads();
    }

    // ---- block reduction -> one partial per block, plain store (no atomics)
    #pragma unroll
    for (int off = 32; off > 0; off >>= 1)
        lsum += __shfl_down(lsum, off, 64);
    if (lane == 0) wred[wv] = (double)lsum;
    __syncthreads();
    if (tid == 0) {
        const int bid = blockIdx.x + GX * (blockIdx.y + GYB * blockIdx.z);
        partials[bid] = wred[0] + wred[1] + wred[2] + wred[3];
    }
}

// 1 block x 1024 threads: independent loads per thread, then tree-reduce.
__global__ __launch_bounds__(1024) void ssim_finalize_kernel(
    const double* __restrict__ partials, float* __restrict__ out)
{
    __shared__ double wred[16];
    const int tid  = threadIdx.x;
    const int lane = tid & 63;
    const int wv   = tid >> 6;
    double s = 0.0;
    #pragma unroll
    for (int i = 0; i < 5; ++i) {                 // 5*1024 >= 4224
        const int idx = tid + i * 1024;
        if (idx < NBLOCKS) s += partials[idx];
    }
    #pragma unroll
    for (int off = 32; off > 0; off >>= 1)
        s += __shfl_down(s, off, 64);
    if (lane == 0) wred[wv] = s;
    __syncthreads();
    if (wv == 0) {
        double v = (lane < 16) ? wred[lane] : 0.0;
        v += __shfl_down(v, 8, 64);
        v += __shfl_down(v, 4, 64);
        v += __shfl_down(v, 2, 64);
        v += __shfl_down(v, 1, 64);
        if (lane == 0) out[0] = (float)(v / (double)N_ELEM);
    }
}

extern "C" void kernel_launch(void* const* d_in, const int* in_sizes, int n_in,
                              void* d_out, int out_size, void* d_ws, size_t ws_size,
                              hipStream_t stream)
{
    const float* img1 = (const float*)d_in[0];
    const float* img2 = (const float*)d_in[1];
    double* partials  = (double*)d_ws;           // 4224 * 8B = 33.8 KB scratch
    float* out        = (float*)d_out;

    dim3 grid(GX, GYB, NPLANES);
    ssim_tile_kernel<<<grid, dim3(256), 0, stream>>>(img1, img2, partials);
    ssim_finalize_kernel<<<1, dim3(1024), 0, stream>>>(partials, out);
}

// Round 6
// 136.865 us; speedup vs baseline: 3.2192x; 1.0097x over previous
//
#include <hip/hip_runtime.h>
#include <cstdint>

#define IMG_H 512
#define IMG_W 512
#define ROW_BYTES (IMG_W * 4)
#define NPLANES 48                  // 16 batch * 3 channels
#define PLANE_SZ (IMG_H * IMG_W)
#define N_ELEM (NPLANES * PLANE_SZ) // 12,582,912

#define TILE_W 48
#define TILE_H 32
#define GX 11
#define GY 16
#define NBLOCKS (GX * GY * NPLANES) // 8448
#define VPITCH 59                   // stored halo cols 0..57 (+1 pad)

#define SSIM_C1 1e-4f
#define SSIM_C2 9e-4f

// Raw buffer load: OOB (row<0 / row>=H via soffset; bad col via huge voffset)
// returns 0.0f in hardware = free 'SAME' zero padding, zero bounds VALU.
typedef int rsrc_t __attribute__((ext_vector_type(4)));
__device__ float
llvm_amdgcn_raw_buffer_load_fp32(rsrc_t srsrc, int voffset, int soffset,
                                 int glc_slc) __asm("llvm.amdgcn.raw.buffer.load.f32");

__device__ inline rsrc_t make_rsrc(const void* p, int bytes) {
    rsrc_t r;
    r.x = (int)(uint32_t)(uintptr_t)p;       // base lo
    r.y = (int)((uintptr_t)p >> 32);         // base hi, stride=0
    r.z = bytes;                             // num_records (bytes)
    r.w = 0x00020000;                        // raw dword SRD word3
    return r;
}

// Separable 11x11 Gaussian over 4 channels (s=x+y, d=x-y, s^2, d^2),
// SSIM map, per-block partial.
//
// Journal: R5(occupancy) neutral; R6/R7(pk-f32) dead end; R8(fused finalize
// via device atomic) catastrophic (serial cross-XCD atomic chain); R9(2-tile
// reg prefetch) regressed (compiler won't hold 36 loads in flight; VGPR=56).
// R10 = R0 exactly, minus the inter-pass __syncthreads(): wave wv's vertical
// writes vs rows [8wv,8wv+8) and its horizontal (r = tid>>3) reads exactly
// those rows -> the dependency is wave-internal. An in-wave lgkmcnt(0) fence
// replaces the block barrier, so the 4 waves run fully decoupled and SIMD
// phases drift instead of stalling in lockstep on load-return + barrier.
__global__ __launch_bounds__(256, 4) void ssim_tile_kernel(
    const float* __restrict__ img1, const float* __restrict__ img2,
    double* __restrict__ partials)
{
    __shared__ float4 vs[TILE_H][VPITCH]; // 30.2 KB -> 5 blocks/CU
    __shared__ double wred[4];

    // exact gaussian(ws=11, sigma=1.5) weights (normalized, ~1e-8 abs)
    const float gw[11] = {0.00102838f, 0.00759876f, 0.03600077f, 0.10936069f,
                          0.21300553f, 0.26601172f, 0.21300553f, 0.10936069f,
                          0.03600077f, 0.00759876f, 0.00102838f};

    const int tid  = threadIdx.x;
    const int lane = tid & 63;
    const int wv   = tid >> 6;
    const int ox = blockIdx.x * TILE_W;
    const int oy = blockIdx.y * TILE_H;

    const float* p1 = img1 + (size_t)blockIdx.z * PLANE_SZ;
    const float* p2 = img2 + (size_t)blockIdx.z * PLANE_SZ;
    const rsrc_t rr1 = make_rsrc(p1, PLANE_SZ * 4);
    const rsrc_t rr2 = make_rsrc(p2, PLANE_SZ * 4);

    // ---- vertical pass: wave wv -> output rows [oy+wv*8, +8), lane = halo col
    {
        const int r0 = wv * 8;
        const int srow0 = __builtin_amdgcn_readfirstlane(oy + r0 - 5); // SGPR
        const int gcol = ox + lane - 5;
        // lanes >= 58 are never consumed by the horizontal pass: mask their
        // (otherwise in-bounds) loads too -> less vertical fetch traffic.
        const int coff = (lane < 58 && (unsigned)gcol < (unsigned)IMG_W)
                             ? (gcol * 4) : 0x48000000;

        // Stage 1: issue ALL 36 loads back-to-back (max memory-level parallelism)
        float xs[18], ys[18];
        #pragma unroll
        for (int i = 0; i < 18; ++i) {
            const int soff = (srow0 + i) * ROW_BYTES;  // SGPR soffset
            xs[i] = llvm_amdgcn_raw_buffer_load_fp32(rr1, coff, soff, 0);
            ys[i] = llvm_amdgcn_raw_buffer_load_fp32(rr2, coff, soff, 0);
        }

        // Stage 2: consume
        float4 acc[8];
        #pragma unroll
        for (int o = 0; o < 8; ++o) acc[o] = make_float4(0.f, 0.f, 0.f, 0.f);
        #pragma unroll
        for (int i = 0; i < 18; ++i) {
            const float s = xs[i] + ys[i], d = xs[i] - ys[i];
            const float s2 = s * s, d2 = d * d;
            #pragma unroll
            for (int o = 0; o < 8; ++o) {
                const int k = i - o;              // tap index (static)
                if (k >= 0 && k <= 10) {
                    const float w = gw[k];
                    acc[o].x = fmaf(w, s,  acc[o].x);
                    acc[o].y = fmaf(w, d,  acc[o].y);
                    acc[o].z = fmaf(w, s2, acc[o].z);
                    acc[o].w = fmaf(w, d2, acc[o].w);
                }
            }
        }
        if (lane < 58) {                          // only cols used by horizontal
            #pragma unroll
            for (int o = 0; o < 8; ++o) vs[r0 + o][lane] = acc[o];
        }
    }

    // Wave-internal fence: drain this wave's ds_writes before its ds_reads.
    // (No __syncthreads(): wave wv reads ONLY the rows it wrote.)
    asm volatile("s_waitcnt lgkmcnt(0)" ::: "memory");

    // ---- horizontal pass + SSIM: thread -> 1 row x 6 consecutive cols
    // r = tid>>3 for tid in wave wv spans exactly rows [8wv, 8wv+8)  -> wave-private.
    float lsum = 0.f;
    {
        const int r  = tid >> 3;
        const int c0 = (tid & 7) * 6;            // max read col 42+15=57 < 58
        float4 m[6];
        #pragma unroll
        for (int j = 0; j < 6; ++j) m[j] = make_float4(0.f, 0.f, 0.f, 0.f);
        #pragma unroll
        for (int t = 0; t < 16; ++t) {
            const float4 v = vs[r][c0 + t];
            #pragma unroll
            for (int j = 0; j < 6; ++j) {
                const int k = t - j;
                if (k >= 0 && k <= 10) {
                    const float w = gw[k];
                    m[j].x = fmaf(w, v.x, m[j].x);
                    m[j].y = fmaf(w, v.y, m[j].y);
                    m[j].z = fmaf(w, v.z, m[j].z);
                    m[j].w = fmaf(w, v.w, m[j].w);
                }
            }
        }
        #pragma unroll
        for (int j = 0; j < 6; ++j) {
            if (ox + c0 + j < IMG_W) {           // clip right-edge partial tile
                const float mus = m[j].x, mud = m[j].y;
                const float es2 = m[j].z, ed2 = m[j].w;
                const float a = mus * mus, b = mud * mud;
                // mu1 = (mus+mud)/2, mu2 = (mus-mud)/2:
                const float num1 = (a - b) * 0.5f + SSIM_C1;               // 2*mu1*mu2 + C1
                const float den1 = (a + b) * 0.5f + SSIM_C1;               // mu1^2+mu2^2 + C1
                const float num2 = (es2 - ed2 - (a - b)) * 0.5f + SSIM_C2; // 2*sigma12 + C2
                const float den2 = (es2 + ed2 - (a + b)) * 0.5f + SSIM_C2; // s1+s2 + C2
                lsum += (num1 * num2) * __builtin_amdgcn_rcpf(den1 * den2);
            }
        }
    }

    // ---- block reduction -> one partial per block, plain store (no atomics)
    #pragma unroll
    for (int off = 32; off > 0; off >>= 1)
        lsum += __shfl_down(lsum, off, 64);
    if (lane == 0) wred[wv] = (double)lsum;
    __syncthreads();                              // only barrier in the kernel
    if (tid == 0) {
        const int bid = blockIdx.x + GX * (blockIdx.y + GY * blockIdx.z);
        partials[bid] = wred[0] + wred[1] + wred[2] + wred[3];
    }
}

// 1 block x 1024 threads: ~8 independent loads per thread, then tree-reduce.
__global__ __launch_bounds__(1024) void ssim_finalize_kernel(
    const double* __restrict__ partials, float* __restrict__ out)
{
    __shared__ double wred[16];
    const int tid  = threadIdx.x;
    const int lane = tid & 63;
    const int wv   = tid >> 6;
    double s = 0.0;
    #pragma unroll
    for (int i = 0; i < 9; ++i) {
        const int idx = tid + i * 1024;
        if (idx < NBLOCKS) s += partials[idx];
    }
    #pragma unroll
    for (int off = 32; off > 0; off >>= 1)
        s += __shfl_down(s, off, 64);
    if (lane == 0) wred[wv] = s;
    __syncthreads();
    if (wv == 0) {
        double v = (lane < 16) ? wred[lane] : 0.0;
        v += __shfl_down(v, 8, 64);
        v += __shfl_down(v, 4, 64);
        v += __shfl_down(v, 2, 64);
        v += __shfl_down(v, 1, 64);
        if (lane == 0) out[0] = (float)(v / (double)N_ELEM);
    }
}

extern "C" void kernel_launch(void* const* d_in, const int* in_sizes, int n_in,
                              void* d_out, int out_size, void* d_ws, size_t ws_size,
                              hipStream_t stream)
{
    const float* img1 = (const float*)d_in[0];
    const float* img2 = (const float*)d_in[1];
    double* partials  = (double*)d_ws;          // 8448 * 8B = 67.6 KB scratch
    float* out        = (float*)d_out;

    dim3 grid(GX, GY, NPLANES);
    ssim_tile_kernel<<<grid, dim3(256), 0, stream>>>(img1, img2, partials);
    ssim_finalize_kernel<<<1, dim3(1024), 0, stream>>>(partials, out);
}

// Round 7
// 136.060 us; speedup vs baseline: 3.2383x; 1.0059x over previous
//
#include <hip/hip_runtime.h>
#include <cstdint>

#define IMG_H 512
#define IMG_W 512
#define ROW_BYTES (IMG_W * 4)
#define NPLANES 48                  // 16 batch * 3 channels
#define PLANE_SZ (IMG_H * IMG_W)
#define N_ELEM (NPLANES * PLANE_SZ) // 12,582,912

#define TILE_W 48
#define TILE_H 32
#define GX 11
#define GY 16
#define TILES_PER_PLANE (GX * GY)    // 176
#define NBLOCKS (TILES_PER_PLANE * NPLANES) // 8448 = 8 * 1056
#define NXCD 8
#define CHUNK (NBLOCKS / NXCD)       // 1056 = 6 planes per XCD
#define VPITCH 59                   // stored halo cols 0..57 (+1 pad)

#define SSIM_C1 1e-4f
#define SSIM_C2 9e-4f

// Raw buffer load: OOB (row<0 / row>=H via soffset; bad col via huge voffset)
// returns 0.0f in hardware = free 'SAME' zero padding, zero bounds VALU.
typedef int rsrc_t __attribute__((ext_vector_type(4)));
__device__ float
llvm_amdgcn_raw_buffer_load_fp32(rsrc_t srsrc, int voffset, int soffset,
                                 int glc_slc) __asm("llvm.amdgcn.raw.buffer.load.f32");

__device__ inline rsrc_t make_rsrc(const void* p, int bytes) {
    rsrc_t r;
    r.x = (int)(uint32_t)(uintptr_t)p;       // base lo
    r.y = (int)((uintptr_t)p >> 32);         // base hi, stride=0
    r.z = bytes;                             // num_records (bytes)
    r.w = 0x00020000;                        // raw dword SRD word3
    return r;
}

// Separable 11x11 Gaussian over 4 channels (s=x+y, d=x-y, s^2, d^2),
// SSIM map, per-block partial.
//
// Journal: R5(occupancy) neutral; R6/R7(pk-f32) dead end (pk saves issue
// slots, not FP32-pipe execution cycles); R8(fused finalize, device atomic)
// catastrophic; R9(2-tile reg prefetch) regressed (compiler chunks loads);
// R10 (drop inter-pass barrier; wave-private LDS rows + lgkmcnt fence) WIN:
// 51 -> 46.4us, VALUBusy 67%. R11 = R10 + XCD-aware swizzle (T1): dispatch
// round-robins consecutive bids over 8 XCDs, so halo-sharing neighbor tiles
// landed on different non-coherent L2s (FETCH 123MB vs 100.6 ideal). With
// NBLOCKS = 8*1056, swz=(bid%8)*1056+bid/8 gives each XCD 6 whole planes ->
// all halo re-reads XCD-local -> L2 hits -> shorter load drain.
__global__ __launch_bounds__(256, 4) void ssim_tile_kernel(
    const float* __restrict__ img1, const float* __restrict__ img2,
    double* __restrict__ partials)
{
    __shared__ float4 vs[TILE_H][VPITCH]; // 30.2 KB -> 5 blocks/CU
    __shared__ double wred[4];

    // exact gaussian(ws=11, sigma=1.5) weights (normalized, ~1e-8 abs)
    const float gw[11] = {0.00102838f, 0.00759876f, 0.03600077f, 0.10936069f,
                          0.21300553f, 0.26601172f, 0.21300553f, 0.10936069f,
                          0.03600077f, 0.00759876f, 0.00102838f};

    const int tid  = threadIdx.x;
    const int lane = tid & 63;
    const int wv   = tid >> 6;

    // ---- XCD-aware swizzle: contiguous work chunk per XCD (bijective,
    // NBLOCKS % 8 == 0). Decode spatial indices from the swizzled id.
    const int bid  = blockIdx.x;
    const int swz  = (bid & (NXCD - 1)) * CHUNK + (bid >> 3);
    const int tx    = swz % GX;
    const int tyz   = swz / GX;
    const int ty    = tyz % GY;
    const int plane = tyz / GY;

    const int ox = tx * TILE_W;
    const int oy = ty * TILE_H;

    const float* p1 = img1 + (size_t)plane * PLANE_SZ;
    const float* p2 = img2 + (size_t)plane * PLANE_SZ;
    const rsrc_t rr1 = make_rsrc(p1, PLANE_SZ * 4);
    const rsrc_t rr2 = make_rsrc(p2, PLANE_SZ * 4);

    // ---- vertical pass: wave wv -> output rows [oy+wv*8, +8), lane = halo col
    {
        const int r0 = wv * 8;
        const int srow0 = __builtin_amdgcn_readfirstlane(oy + r0 - 5); // SGPR
        const int gcol = ox + lane - 5;
        // lanes >= 58 are never consumed by the horizontal pass: mask their
        // (otherwise in-bounds) loads too -> less vertical fetch traffic.
        const int coff = (lane < 58 && (unsigned)gcol < (unsigned)IMG_W)
                             ? (gcol * 4) : 0x48000000;

        // Stage 1: issue ALL 36 loads back-to-back (max memory-level parallelism)
        float xs[18], ys[18];
        #pragma unroll
        for (int i = 0; i < 18; ++i) {
            const int soff = (srow0 + i) * ROW_BYTES;  // SGPR soffset
            xs[i] = llvm_amdgcn_raw_buffer_load_fp32(rr1, coff, soff, 0);
            ys[i] = llvm_amdgcn_raw_buffer_load_fp32(rr2, coff, soff, 0);
        }

        // Stage 2: consume
        float4 acc[8];
        #pragma unroll
        for (int o = 0; o < 8; ++o) acc[o] = make_float4(0.f, 0.f, 0.f, 0.f);
        #pragma unroll
        for (int i = 0; i < 18; ++i) {
            const float s = xs[i] + ys[i], d = xs[i] - ys[i];
            const float s2 = s * s, d2 = d * d;
            #pragma unroll
            for (int o = 0; o < 8; ++o) {
                const int k = i - o;              // tap index (static)
                if (k >= 0 && k <= 10) {
                    const float w = gw[k];
                    acc[o].x = fmaf(w, s,  acc[o].x);
                    acc[o].y = fmaf(w, d,  acc[o].y);
                    acc[o].z = fmaf(w, s2, acc[o].z);
                    acc[o].w = fmaf(w, d2, acc[o].w);
                }
            }
        }
        if (lane < 58) {                          // only cols used by horizontal
            #pragma unroll
            for (int o = 0; o < 8; ++o) vs[r0 + o][lane] = acc[o];
        }
    }

    // Wave-internal fence: drain this wave's ds_writes before its ds_reads.
    // (No __syncthreads(): wave wv reads ONLY the rows it wrote.)
    asm volatile("s_waitcnt lgkmcnt(0)" ::: "memory");

    // ---- horizontal pass + SSIM: thread -> 1 row x 6 consecutive cols
    // r = tid>>3 for tid in wave wv spans exactly rows [8wv, 8wv+8) -> wave-private.
    float lsum = 0.f;
    {
        const int r  = tid >> 3;
        const int c0 = (tid & 7) * 6;            // max read col 42+15=57 < 58
        float4 m[6];
        #pragma unroll
        for (int j = 0; j < 6; ++j) m[j] = make_float4(0.f, 0.f, 0.f, 0.f);
        #pragma unroll
        for (int t = 0; t < 16; ++t) {
            const float4 v = vs[r][c0 + t];
            #pragma unroll
            for (int j = 0; j < 6; ++j) {
                const int k = t - j;
                if (k >= 0 && k <= 10) {
                    const float w = gw[k];
                    m[j].x = fmaf(w, v.x, m[j].x);
                    m[j].y = fmaf(w, v.y, m[j].y);
                    m[j].z = fmaf(w, v.z, m[j].z);
                    m[j].w = fmaf(w, v.w, m[j].w);
                }
            }
        }
        #pragma unroll
        for (int j = 0; j < 6; ++j) {
            if (ox + c0 + j < IMG_W) {           // clip right-edge partial tile
                const float mus = m[j].x, mud = m[j].y;
                const float es2 = m[j].z, ed2 = m[j].w;
                const float a = mus * mus, b = mud * mud;
                // mu1 = (mus+mud)/2, mu2 = (mus-mud)/2:
                const float num1 = (a - b) * 0.5f + SSIM_C1;               // 2*mu1*mu2 + C1
                const float den1 = (a + b) * 0.5f + SSIM_C1;               // mu1^2+mu2^2 + C1
                const float num2 = (es2 - ed2 - (a - b)) * 0.5f + SSIM_C2; // 2*sigma12 + C2
                const float den2 = (es2 + ed2 - (a + b)) * 0.5f + SSIM_C2; // s1+s2 + C2
                lsum += (num1 * num2) * __builtin_amdgcn_rcpf(den1 * den2);
            }
        }
    }

    // ---- block reduction -> one partial per block, plain store (no atomics)
    #pragma unroll
    for (int off = 32; off > 0; off >>= 1)
        lsum += __shfl_down(lsum, off, 64);
    if (lane == 0) wred[wv] = (double)lsum;
    __syncthreads();                              // only barrier in the kernel
    if (tid == 0) {
        partials[bid] = wred[0] + wred[1] + wred[2] + wred[3];
    }
}

// 1 block x 1024 threads: ~8 independent loads per thread, then tree-reduce.
__global__ __launch_bounds__(1024) void ssim_finalize_kernel(
    const double* __restrict__ partials, float* __restrict__ out)
{
    __shared__ double wred[16];
    const int tid  = threadIdx.x;
    const int lane = tid & 63;
    const int wv   = tid >> 6;
    double s = 0.0;
    #pragma unroll
    for (int i = 0; i < 9; ++i) {
        const int idx = tid + i * 1024;
        if (idx < NBLOCKS) s += partials[idx];
    }
    #pragma unroll
    for (int off = 32; off > 0; off >>= 1)
        s += __shfl_down(s, off, 64);
    if (lane == 0) wred[wv] = s;
    __syncthreads();
    if (wv == 0) {
        double v = (lane < 16) ? wred[lane] : 0.0;
        v += __shfl_down(v, 8, 64);
        v += __shfl_down(v, 4, 64);
        v += __shfl_down(v, 2, 64);
        v += __shfl_down(v, 1, 64);
        if (lane == 0) out[0] = (float)(v / (double)N_ELEM);
    }
}

extern "C" void kernel_launch(void* const* d_in, const int* in_sizes, int n_in,
                              void* d_out, int out_size, void* d_ws, size_t ws_size,
                              hipStream_t stream)
{
    const float* img1 = (const float*)d_in[0];
    const float* img2 = (const float*)d_in[1];
    double* partials  = (double*)d_ws;          // 8448 * 8B = 67.6 KB scratch
    float* out        = (float*)d_out;

    ssim_tile_kernel<<<dim3(NBLOCKS), dim3(256), 0, stream>>>(img1, img2, partials);
    ssim_finalize_kernel<<<1, dim3(1024), 0, stream>>>(partials, out);
}